// Round 1
// baseline (399.262 us; speedup 1.0000x reference)
//
#include <hip/hip_runtime.h>

typedef unsigned short u16;
typedef unsigned int u32;
typedef __bf16 bf16x8 __attribute__((ext_vector_type(8)));
typedef float f32x4 __attribute__((ext_vector_type(4)));
typedef float f32x16 __attribute__((ext_vector_type(16)));

__device__ __forceinline__ float b2f(u16 u) { return __uint_as_float(((u32)u) << 16); }
__device__ __forceinline__ u16 f2b(float f) {
  u32 u = __float_as_uint(f);
  u += 0x7fffu + ((u >> 16) & 1u);   // round-to-nearest-even
  return (u16)(u >> 16);
}

// async global->LDS, 16B per lane; lds dest = wave-uniform base + lane*16
__device__ __forceinline__ void gll16(const u16* g, u16* l) {
  __builtin_amdgcn_global_load_lds(
      (const __attribute__((address_space(1))) void*)g,
      (__attribute__((address_space(3))) void*)l, 16, 0, 0);
}

// load 4 consecutive elements, dtype-polymorphic (uniform branch)
__device__ __forceinline__ float4 load4(const void* p, size_t idx, bool f32) {
  if (f32) return *(const float4*)((const float*)p + idx);
  ushort4 u = *(const ushort4*)((const u16*)p + idx);
  return make_float4(b2f(u.x), b2f(u.y), b2f(u.z), b2f(u.w));
}

// ---------------------------------------------------------------- dtype sniff
__global__ __launch_bounds__(256) void detect_kernel(const u16* __restrict__ sig,
                                                     int* __restrict__ flag) {
  __shared__ int cnt;
  if (threadIdx.x == 0) cnt = 0;
  __syncthreads();
  int c = 0;
  for (int i = threadIdx.x; i < 16384; i += 256) {
    u16 v = sig[i];
    c += ((v & 0x7F80u) == 0x7F80u) ? 1 : 0;
  }
  atomicAdd(&cnt, c);
  __syncthreads();
  if (threadIdx.x == 0) *flag = (cnt >= 8) ? 1 : 0;
}

// ---------------------------------------------------------------- LN + var-prop
__global__ __launch_bounds__(256) void ln_prep_kernel(
    const int* __restrict__ flag,
    const void* __restrict__ mu, const void* __restrict__ sigma,
    const void* __restrict__ gamma, const void* __restrict__ beta,
    u16* __restrict__ mu_n, u16* __restrict__ a1sg)
{
  __shared__ float ps[4], pq[4];
  const bool f32 = (*flag != 0);
  const int t = threadIdx.x;
  const int wv = t >> 6, lane = t & 63;
  const size_t base = (size_t)blockIdx.x * 1024 + (size_t)t * 4;
  float4 xm = load4(mu, base, f32);
  float4 xs = load4(sigma, base, f32);
  float x0 = xm.x, x1 = xm.y, x2 = xm.z, x3 = xm.w;
  float s0 = xs.x, s1 = xs.y, s2 = xs.z, s3 = xs.w;

  float sv = x0 + x1 + x2 + x3;
  float qv = x0*x0 + x1*x1 + x2*x2 + x3*x3;
  #pragma unroll
  for (int off = 32; off > 0; off >>= 1) {
    sv += __shfl_xor(sv, off, 64);
    qv += __shfl_xor(qv, off, 64);
  }
  if (lane == 0) { ps[wv] = sv; pq[wv] = qv; }
  __syncthreads();
  float sum = ps[0] + ps[1] + ps[2] + ps[3];
  float ssq = pq[0] + pq[1] + pq[2] + pq[3];

  float mean = sum * (1.0f / 1024.0f);
  float var  = ssq * (1.0f / 1024.0f) - mean * mean;
  float inv  = 1.0f / sqrtf(var + 1e-5f);
  float inv2 = inv * inv;

  float4 g4 = load4(gamma, (size_t)t * 4, f32);
  float4 b4 = load4(beta, (size_t)t * 4, f32);

  float m0 = (x0 - mean) * inv * g4.x + b4.x;
  float m1 = (x1 - mean) * inv * g4.y + b4.y;
  float m2 = (x2 - mean) * inv * g4.z + b4.z;
  float m3 = (x3 - mean) * inv * g4.w + b4.w;
  float v0 = s0 * g4.x * g4.x * inv2;
  float v1 = s1 * g4.y * g4.y * inv2;
  float v2 = s2 * g4.z * g4.z * inv2;
  float v3 = s3 * g4.w * g4.w * inv2;

  ushort4 omu = { f2b(m0), f2b(m1), f2b(m2), f2b(m3) };
  ushort4 oa1 = { f2b(m0*m0 + v0), f2b(m1*m1 + v1), f2b(m2*m2 + v2), f2b(m3*m3 + v3) };
  ushort4 osg = { f2b(v0), f2b(v1), f2b(v2), f2b(v3) };
  *(ushort4*)(mu_n + base) = omu;
  size_t r2 = (size_t)blockIdx.x * 2048 + (size_t)t * 4;
  *(ushort4*)(a1sg + r2) = oa1;
  *(ushort4*)(a1sg + r2 + 1024) = osg;
}

// ---------------------------------------------------------------- weight prep (fused)
// blocks cover qkv weights then out weights; per-block branch is uniform.
__global__ __launch_bounds__(256) void wprep_kernel(
    const int* __restrict__ flag,
    const void* __restrict__ wq_mu, const void* __restrict__ wq_sraw,
    u16* __restrict__ q_bf, u16* __restrict__ q_s2,
    const void* __restrict__ wo_mu, const void* __restrict__ wo_sraw,
    u16* __restrict__ o_bf, u16* __restrict__ o_s2, int nq)
{
  const bool f32 = (*flag != 0);
  size_t idx = ((size_t)blockIdx.x * 256 + threadIdx.x) * 4;
  const void *wmu, *wsr; u16 *obf, *os2;
  if (idx < (size_t)nq) { wmu = wq_mu; wsr = wq_sraw; obf = q_bf; os2 = q_s2; }
  else { idx -= nq; wmu = wo_mu; wsr = wo_sraw; obf = o_bf; os2 = o_s2; }
  int row = (int)(idx >> 10), k = (int)(idx & 1023);
  float4 m4 = load4(wmu, idx, f32);
  float4 s4 = load4(wsr, idx, f32);
  float m[4] = { m4.x, m4.y, m4.z, m4.w };
  float s[4] = { s4.x, s4.y, s4.z, s4.w };
  ushort4 ob, os, oq;
  u16* obp = (u16*)&ob; u16* osp = (u16*)&os; u16* oqp = (u16*)&oq;
  #pragma unroll
  for (int i = 0; i < 4; ++i) {
    float sp = (s[i] > 15.f) ? s[i] : log1pf(__expf(s[i]));
    obp[i] = f2b(m[i]);
    osp[i] = f2b(sp);
    oqp[i] = f2b(m[i] * m[i]);
  }
  *(ushort4*)(obf + idx) = ob;
  size_t r2 = (size_t)row * 2048 + k;
  *(ushort4*)(os2 + r2) = os;
  *(ushort4*)(os2 + r2 + 1024) = oq;
}

// ---------------------------------------------------------------- paired GEMM (32x32x16 MFMA)
// Two independent C = A·B^T GEMMs in one dispatch; blockIdx.x < split -> GEMM 0.
// BK=64, global_load_lds w=16, XOR-swizzled LDS (seg ^= row&7): conflict-free.
// Wave tile 64x64 = 2x2 fragments of 32x32. C/D: col=lane&31,
// row=(reg&3)+8*(reg>>2)+4*(lane>>5)  [HW-verified m74/m101].
template<bool DYN>
__global__ __launch_bounds__(256, 4) void gemm_pair_kernel(
    const u16* __restrict__ A0, const u16* __restrict__ B0, int K0, void* C0, size_t ob0,
    const u16* __restrict__ A1, const u16* __restrict__ B1, int K1, void* C1, size_t ob1,
    int split, int N, const int* __restrict__ flag)
{
  __shared__ u16 lA[128 * 64];
  __shared__ u16 lB[128 * 64];
  const int t = threadIdx.x;
  int bx = blockIdx.x;
  const u16 *A, *B; void* C; size_t obase; int K;
  if (bx < split) { A = A0; B = B0; K = K0; C = C0; obase = ob0; }
  else { bx -= split; A = A1; B = B1; K = K1; C = C1; obase = ob1; }

  const int n0 = bx * 128, m0 = blockIdx.y * 128;
  const int lane = t & 63, wave = t >> 6;
  const int wr = (wave >> 1) * 64, wc = (wave & 1) * 64;
  const int m31 = lane & 31, h5 = lane >> 5;
  const int mx = m31 & 7;               // reader swizzle key

  const int srow = t >> 3;
  const int gseg = (t & 7) ^ (srow & 7);

  f32x16 acc[2][2];
  #pragma unroll
  for (int i = 0; i < 2; ++i)
    #pragma unroll
    for (int j = 0; j < 2; ++j)
      #pragma unroll
      for (int r = 0; r < 16; ++r) acc[i][j][r] = 0.f;

  for (int k0 = 0; k0 < K; k0 += 64) {
    __syncthreads();
    #pragma unroll
    for (int rep = 0; rep < 4; ++rep) {
      gll16(A + (size_t)(m0 + srow + rep * 32) * K + k0 + gseg * 8,
            lA + rep * 2048 + wave * 512);
      gll16(B + (size_t)(n0 + srow + rep * 32) * K + k0 + gseg * 8,
            lB + rep * 2048 + wave * 512);
    }
    __syncthreads();
    #pragma unroll
    for (int ks = 0; ks < 4; ++ks) {
      const int seg = ks * 2 + h5;
      bf16x8 af[2], bfr[2];
      #pragma unroll
      for (int tm = 0; tm < 2; ++tm)
        af[tm] = *(const bf16x8*)&lA[(wr + tm * 32 + m31) * 64 + (seg ^ mx) * 8];
      #pragma unroll
      for (int tn = 0; tn < 2; ++tn)
        bfr[tn] = *(const bf16x8*)&lB[(wc + tn * 32 + m31) * 64 + (seg ^ mx) * 8];
      #pragma unroll
      for (int tm = 0; tm < 2; ++tm)
        #pragma unroll
        for (int tn = 0; tn < 2; ++tn)
          acc[tm][tn] = __builtin_amdgcn_mfma_f32_32x32x16_bf16(af[tm], bfr[tn], acc[tm][tn], 0, 0, 0);
    }
  }

  const bool of32 = DYN && (*flag != 0);
  #pragma unroll
  for (int tm = 0; tm < 2; ++tm)
    #pragma unroll
    for (int tn = 0; tn < 2; ++tn) {
      int colb = n0 + wc + tn * 32 + m31;
      #pragma unroll
      for (int r = 0; r < 16; ++r) {
        int row = m0 + wr + tm * 32 + (r & 3) + 8 * (r >> 2) + 4 * h5;
        float v = acc[tm][tn][r];
        size_t off = obase + (size_t)row * N + colb;
        if (DYN) {
          if (of32) ((float*)C)[off] = v;
          else      ((u16*)C)[off] = f2b(v);
        } else {
          ((u16*)C)[off] = f2b(v);
        }
      }
    }
}

// ---------------------------------------------------------------- attention pass 1
// Sum of exp over mu scores (no max: |s| <= ~3 << 88, fp32 exp exact-safe).
__global__ __launch_bounds__(256) void attn_pass1(
    const u16* __restrict__ qkv_mu, float* __restrict__ invl)
{
  __shared__ u16 lK[128 * 72];
  const int t = threadIdx.x;
  const int wv = t >> 6, lane = t & 63;
  const int ml = lane & 15, qd = lane >> 4;
  const int bh = blockIdx.y;
  const int b = bh >> 4, h = bh & 15;
  const size_t rowbase = (size_t)b * 1024 * 3072;
  const int i0 = blockIdx.x * 64;
  const int qcol = h * 64, kcol = 1024 + h * 64;
  const int qrow = wv * 16;

  bf16x8 aQm[2];
  #pragma unroll
  for (int ks = 0; ks < 2; ++ks)
    aQm[ks] = *(const bf16x8*)(qkv_mu + rowbase +
        (size_t)(i0 + qrow + ml) * 3072 + qcol + ks * 32 + qd * 8);

  float lsum[4] = {0.f, 0.f, 0.f, 0.f};

  for (int j0 = 0; j0 < 1024; j0 += 128) {
    __syncthreads();
    #pragma unroll
    for (int rep = 0; rep < 4; ++rep) {
      int c = t + rep * 256;
      int row = c >> 3, seg = c & 7;
      *(uint4*)&lK[row * 72 + seg * 8] =
          *(const uint4*)(qkv_mu + rowbase + (size_t)(j0 + row) * 3072 + kcol + seg * 8);
    }
    __syncthreads();
    #pragma unroll
    for (int tj = 0; tj < 8; ++tj) {
      bf16x8 b0 = *(const bf16x8*)&lK[(tj * 16 + ml) * 72 + qd * 8];
      bf16x8 b1 = *(const bf16x8*)&lK[(tj * 16 + ml) * 72 + 32 + qd * 8];
      f32x4 s = (f32x4){0.f, 0.f, 0.f, 0.f};
      s = __builtin_amdgcn_mfma_f32_16x16x32_bf16(aQm[0], b0, s, 0, 0, 0);
      s = __builtin_amdgcn_mfma_f32_16x16x32_bf16(aQm[1], b1, s, 0, 0, 0);
      #pragma unroll
      for (int r = 0; r < 4; ++r) lsum[r] += __expf(s[r] * 0.125f);
    }
  }
  #pragma unroll
  for (int r = 0; r < 4; ++r) {
    float l = lsum[r];
    #pragma unroll
    for (int xo = 1; xo < 16; xo <<= 1) l += __shfl_xor(l, xo, 64);
    if (ml == 0)
      invl[(size_t)bh * 1024 + i0 + qrow + qd * 4 + r] = 1.0f / l;
  }
}

// ---------------------------------------------------------------- attention pass 2
// 512 threads = 8 waves; Q-block 128 rows, 16 rows/wave; K-tile 64 tokens.
// Separate lW buffer -> 3 barriers/tile (no overlay hazard).
__global__ __launch_bounds__(512, 4) void attn_pass2(
    const u16* __restrict__ qkv_mu, const u16* __restrict__ qkv_sg,
    const float* __restrict__ invl,
    u16* __restrict__ o_mu, u16* __restrict__ a1sgo)
{
  __shared__ u16 lKW[128 * 72];
  __shared__ u16 lV[128 * 72];
  __shared__ u16 lP[128 * 72];
  __shared__ u16 lW[128 * 72];

  const int t = threadIdx.x;
  const int wv = t >> 6, lane = t & 63;
  const int ml = lane & 15, qd = lane >> 4;
  const int bh = blockIdx.y;
  const int b = bh >> 4, h = bh & 15;
  const size_t rowbase = (size_t)b * 1024 * 3072;
  const int i0 = blockIdx.x * 128;
  const int qcol = h * 64, kcol = 1024 + h * 64, vcol = 2048 + h * 64;
  const int qrow = wv * 16;

  bf16x8 aQm[2], aQs[2];
  #pragma unroll
  for (int ks = 0; ks < 2; ++ks) {
    size_t ga = rowbase + (size_t)(i0 + qrow + ml) * 3072 + qcol + ks * 32 + qd * 8;
    aQm[ks] = *(const bf16x8*)(qkv_mu + ga);
    aQs[ks] = *(const bf16x8*)(qkv_sg + ga);
  }

  float lacc[4];
  #pragma unroll
  for (int r = 0; r < 4; ++r)
    lacc[r] = invl[(size_t)bh * 1024 + i0 + qrow + qd * 4 + r];

  f32x4 accm[4], accs[4];
  #pragma unroll
  for (int tj = 0; tj < 4; ++tj) {
    accm[tj] = (f32x4){0.f, 0.f, 0.f, 0.f};
    accs[tj] = (f32x4){0.f, 0.f, 0.f, 0.f};
  }

  for (int j0 = 0; j0 < 1024; j0 += 64) {
    __syncthreads();   // prev PV reads done before restaging
    #pragma unroll
    for (int rep = 0; rep < 2; ++rep) {
      int c = t + rep * 512;
      int row = c >> 3, seg = c & 7;
      const u16* src = (row < 64) ? qkv_mu : qkv_sg;
      int rr = row & 63;
      *(uint4*)&lKW[row * 72 + seg * 8] =
          *(const uint4*)(src + rowbase + (size_t)(j0 + rr) * 3072 + kcol + seg * 8);
    }
    {
      int buf = t >> 8, rem = t & 255;
      int db = rem >> 4, tb = rem & 15;
      const u16* src = buf ? qkv_sg : qkv_mu;
      ushort4 vals[4];
      #pragma unroll
      for (int i = 0; i < 4; ++i)
        vals[i] = *(const ushort4*)(src + rowbase + (size_t)(j0 + tb * 4 + i) * 3072 + vcol + db * 4);
      #pragma unroll
      for (int k = 0; k < 4; ++k) {
        ushort4 o;
        u16* op = (u16*)&o;
        const u16* v0 = (const u16*)&vals[0];
        const u16* v1 = (const u16*)&vals[1];
        const u16* v2 = (const u16*)&vals[2];
        const u16* v3 = (const u16*)&vals[3];
        op[0] = v0[k]; op[1] = v1[k]; op[2] = v2[k]; op[3] = v3[k];
        *(ushort4*)&lV[(buf * 64 + db * 4 + k) * 72 + tb * 4] = o;
      }
    }
    __syncthreads();

    f32x4 sm[4], ss[4];
    #pragma unroll
    for (int tj = 0; tj < 4; ++tj) {
      bf16x8 bm0 = *(const bf16x8*)&lKW[(tj * 16 + ml) * 72 + qd * 8];
      bf16x8 bm1 = *(const bf16x8*)&lKW[(tj * 16 + ml) * 72 + 32 + qd * 8];
      bf16x8 bs0 = *(const bf16x8*)&lKW[(64 + tj * 16 + ml) * 72 + qd * 8];
      bf16x8 bs1 = *(const bf16x8*)&lKW[(64 + tj * 16 + ml) * 72 + 32 + qd * 8];
      f32x4 s = (f32x4){0.f, 0.f, 0.f, 0.f};
      s = __builtin_amdgcn_mfma_f32_16x16x32_bf16(aQm[0], bm0, s, 0, 0, 0);
      s = __builtin_amdgcn_mfma_f32_16x16x32_bf16(aQm[1], bm1, s, 0, 0, 0);
      sm[tj] = s;
      f32x4 s2 = (f32x4){0.f, 0.f, 0.f, 0.f};
      s2 = __builtin_amdgcn_mfma_f32_16x16x32_bf16(aQs[0], bs0, s2, 0, 0, 0);
      s2 = __builtin_amdgcn_mfma_f32_16x16x32_bf16(aQs[1], bs1, s2, 0, 0, 0);
      ss[tj] = s2;
    }

    #pragma unroll
    for (int tj = 0; tj < 4; ++tj)
      #pragma unroll
      for (int r = 0; r < 4; ++r) {
        float p = __expf(sm[tj][r] * 0.125f) * lacc[r];
        float jp = p * (1.0f - p);
        float w = jp * jp * (ss[tj][r] * 0.125f);
        int row = qrow + qd * 4 + r;
        lP[row * 72 + tj * 16 + ml] = f2b(p);
        lW[row * 72 + tj * 16 + ml] = f2b(w);
      }
    __syncthreads();

    bf16x8 ap[2], aw[2];
    #pragma unroll
    for (int ks = 0; ks < 2; ++ks) {
      ap[ks] = *(const bf16x8*)&lP[(qrow + ml) * 72 + ks * 32 + qd * 8];
      aw[ks] = *(const bf16x8*)&lW[(qrow + ml) * 72 + ks * 32 + qd * 8];
    }
    #pragma unroll
    for (int tj = 0; tj < 4; ++tj) {
      bf16x8 vm0 = *(const bf16x8*)&lV[(tj * 16 + ml) * 72 + qd * 8];
      bf16x8 vm1 = *(const bf16x8*)&lV[(tj * 16 + ml) * 72 + 32 + qd * 8];
      bf16x8 vs0 = *(const bf16x8*)&lV[(64 + tj * 16 + ml) * 72 + qd * 8];
      bf16x8 vs1 = *(const bf16x8*)&lV[(64 + tj * 16 + ml) * 72 + 32 + qd * 8];
      accm[tj] = __builtin_amdgcn_mfma_f32_16x16x32_bf16(ap[0], vm0, accm[tj], 0, 0, 0);
      accm[tj] = __builtin_amdgcn_mfma_f32_16x16x32_bf16(ap[1], vm1, accm[tj], 0, 0, 0);
      accs[tj] = __builtin_amdgcn_mfma_f32_16x16x32_bf16(aw[0], vs0, accs[tj], 0, 0, 0);
      accs[tj] = __builtin_amdgcn_mfma_f32_16x16x32_bf16(aw[1], vs1, accs[tj], 0, 0, 0);
    }
  }

  // epilogue: o_mu [row][1024]; a1sgo [row][2048] = [mu^2+sg | sg]
  #pragma unroll
  for (int tj = 0; tj < 4; ++tj)
    #pragma unroll
    for (int r = 0; r < 4; ++r) {
      int row = i0 + qrow + qd * 4 + r;
      int col = h * 64 + tj * 16 + ml;
      size_t rowg = (size_t)b * 1024 + row;
      float om = accm[tj][r], os = accs[tj][r];
      o_mu[rowg * 1024 + col] = f2b(om);
      size_t r2 = rowg * 2048 + col;
      a1sgo[r2] = f2b(fmaf(om, om, os));
      a1sgo[r2 + 1024] = f2b(os);
    }
}

// ---------------------------------------------------------------- launch
extern "C" void kernel_launch(void* const* d_in, const int* in_sizes, int n_in,
                              void* d_out, int out_size, void* d_ws, size_t ws_size,
                              hipStream_t stream)
{
  (void)in_sizes; (void)n_in; (void)out_size; (void)ws_size;
  const void* mu        = d_in[0];
  const void* sigma     = d_in[1];
  const void* gamma     = d_in[2];
  const void* beta      = d_in[3];
  const void* wqkv_mu   = d_in[4];
  const void* wqkv_sraw = d_in[5];
  const void* wout_mu   = d_in[6];
  const void* wout_sraw = d_in[7];

  u16* ws = (u16*)d_ws;
  const size_t R = 4096;  // B*N
  u16* mu_n   = ws;                        // R*1024, reused as mu_o
  u16* a1sg   = mu_n + R * 1024;           // R*2048 [A1|sgn], reused as a1sgo
  u16* wq_bf  = a1sg + R * 2048;           // 3072*1024
  u16* wqs2   = wq_bf + 3072 * 1024;       // 3072*2048 [Wsig|Wmu^2]
  u16* wo_bf  = wqs2 + 3072 * 2048;        // 1024*1024
  u16* wos2   = wo_bf + 1024 * 1024;       // 1024*2048
  u16* mu_qkv = wos2 + 1024 * 2048;        // R*3072
  u16* sg_qkv = mu_qkv + R * 3072;         // R*3072
  int* flag   = (int*)(sg_qkv + R * 3072);
  float* invl = (float*)(flag + 16);       // 64*1024 floats

  u16* mu_o  = mu_n;
  u16* a1sgo = a1sg;

  detect_kernel<<<1, 256, 0, stream>>>((const u16*)sigma, flag);
  ln_prep_kernel<<<4096, 256, 0, stream>>>(flag, mu, sigma, gamma, beta, mu_n, a1sg);
  wprep_kernel<<<(4 * 1024 * 1024) / 1024, 256, 0, stream>>>(
      flag, wqkv_mu, wqkv_sraw, wq_bf, wqs2,
      wout_mu, wout_sraw, wo_bf, wos2, 3072 * 1024);

  // merged QKV GEMMs: mu (K=1024) + sigma (K=2048), N=3072
  gemm_pair_kernel<false><<<dim3(48, 32), 256, 0, stream>>>(
      mu_n, wq_bf, 1024, mu_qkv, 0,
      a1sg, wqs2, 2048, sg_qkv, 0,
      24, 3072, nullptr);

  attn_pass1<<<dim3(16, 64), 256, 0, stream>>>(mu_qkv, invl);
  attn_pass2<<<dim3(8, 64), 512, 0, stream>>>(mu_qkv, sg_qkv, invl, mu_o, a1sgo);

  // merged output GEMMs: mu (K=1024) + sigma (K=2048), N=1024
  gemm_pair_kernel<true><<<dim3(16, 32), 256, 0, stream>>>(
      mu_o, wo_bf, 1024, d_out, 0,
      a1sgo, wos2, 2048, d_out, R * 1024,
      8, 1024, flag);
}